// Round 7
// baseline (416.882 us; speedup 1.0000x reference)
//
#include <hip/hip_runtime.h>
#include <hip/hip_bf16.h>

// ---------------------------------------------------------------------------
// BGE-M3 style scoring: dense (CLS cosine), sparse (scatter-max vocab dot),
// colbert (maxsim).  Shapes: q_hidden [8,128,1024], p_hidden [64,512,1024].
// Out = concat(dense[8,64], sparse[8,64], colbert[8,64]) fp32.
//
// 5-dispatch pipeline:
//   1. conv_zero_tw : fp32->bf16 cast (q|p|W), token weights, zero Mbuf/normsq
//   2. canon_all    : sparse canonicalization (q + p in one grid)
//   3. gemm_bt<0>   : projection GEMM (+normsq) with dense+sparse tail blocks
//   4. gemm_bt<1>   : maxsim GEMM with fused per-col normalization + max
//   5. colbert_reduce
//
// GEMM block order uses an XCD-chunked swizzle (XCD = linear_id & 7): the 8
// blocks sharing a 256KB tile are consecutive same-XCD ids -> tile reused
// back-to-back out of that XCD's L2; per-XCD live set ~4MB = L2 size.
// ---------------------------------------------------------------------------

typedef __bf16 bf16x8 __attribute__((ext_vector_type(8)));
typedef float floatx4 __attribute__((ext_vector_type(4)));
typedef unsigned short ushort8v __attribute__((ext_vector_type(8)));

#define TEMP 0.02f

__device__ __forceinline__ unsigned short f2bf(float f) {
    unsigned u = __float_as_uint(f);
    unsigned r = (u + 0x7FFFu + ((u >> 16) & 1u)) >> 16;  // RNE
    return (unsigned short)r;
}
// order-preserving float<->uint encode for atomicMax on possibly-negative floats
__device__ __forceinline__ unsigned encf(float f) {
    unsigned u = __float_as_uint(f);
    return (u & 0x80000000u) ? ~u : (u | 0x80000000u);
}
__device__ __forceinline__ float decf(unsigned u) {
    return __uint_as_float((u & 0x80000000u) ? (u & 0x7FFFFFFFu) : ~u);
}

__device__ __forceinline__ void async_load16(void* lds, const void* g) {
    __builtin_amdgcn_global_load_lds(
        (__attribute__((address_space(1))) void*)g,
        (__attribute__((address_space(3))) void*)lds,
        16, 0, 0);
}

// ---------------------------------------------------------------------------
// conv_zero_tw: 2 rows per block (17408 blocks).
//  - fp32 -> bf16 cast of q_hidden / p_hidden / colbert_w into one buffer
//    (rows [0,1024)=q, [1024,33792)=p, [33792,34816)=W), ushort8 16B stores
//  - sparse token weight tw[row] = relu(dot(row, sparse_w) + sb) for hidden rows
//  - blocks [0,388) also zero Mbuf+normsq (388*256 words = 97+33 KB exactly)
// ---------------------------------------------------------------------------
__global__ void conv_zero_tw(const float* __restrict__ qh, const float* __restrict__ ph,
                             const float* __restrict__ wsrc, unsigned short* __restrict__ dst,
                             const float* __restrict__ sw, const float* __restrict__ sb,
                             float* __restrict__ tw, unsigned* __restrict__ zbase)
{
    __shared__ float red[4];
    int b = blockIdx.x, t = threadIdx.x;
    if (b < 388) zbase[b * 256 + t] = 0u;
    int r0 = b * 2;
    const float* src;
    bool do_tw = true;
    if (r0 < 1024)       { src = qh   + (size_t)r0 * 1024; }
    else if (r0 < 33792) { src = ph   + (size_t)(r0 - 1024) * 1024; }
    else                 { src = wsrc + (size_t)(r0 - 33792) * 1024; do_tw = false; }
    const float4* s4 = (const float4*)src;
    float4 a = s4[t * 2], c = s4[t * 2 + 1];   // 8 consecutive floats per thread
    ushort8v o;
    o[0] = f2bf(a.x); o[1] = f2bf(a.y); o[2] = f2bf(a.z); o[3] = f2bf(a.w);
    o[4] = f2bf(c.x); o[5] = f2bf(c.y); o[6] = f2bf(c.z); o[7] = f2bf(c.w);
    ((ushort8v*)dst)[(size_t)b * 256 + t] = o;
    if (do_tw) {
        const float4* w4 = (const float4*)sw;
        int wi = (t & 127) * 2;
        float4 wa = w4[wi], wc = w4[wi + 1];
        float acc = a.x * wa.x + a.y * wa.y + a.z * wa.z + a.w * wa.w
                  + c.x * wc.x + c.y * wc.y + c.z * wc.z + c.w * wc.w;
        #pragma unroll
        for (int s = 32; s; s >>= 1) acc += __shfl_down(acc, s, 64);
        if ((t & 63) == 0) red[t >> 6] = acc;   // waves 0,1 -> row r0; 2,3 -> r0+1
        __syncthreads();
        if (t == 0)   tw[r0]     = fmaxf(red[0] + red[1] + sb[0], 0.0f);
        if (t == 128) tw[r0 + 1] = fmaxf(red[2] + red[3] + sb[0], 0.0f);
    }
}

// ---------------------------------------------------------------------------
// canon_all: eff[row,l] = tw if token l is the unique argmax for its id in the
// row (ties -> lowest index) and id not in {0,1,2,3}.  One grid for q and p:
// blocks [0,8) = q rows (L=128); blocks [8,136) = p rows x 2 chunks (L=512).
// ---------------------------------------------------------------------------
__global__ void canon_all(const int* __restrict__ q_ids, const int* __restrict__ p_ids,
                          const float* __restrict__ tw,
                          float* __restrict__ eff_q, float* __restrict__ eff_p)
{
    __shared__ int   sid[512];
    __shared__ float stw[512];
    int b = blockIdx.x, t = threadIdx.x;
    const int* ids; const float* twr; float* eff; int L, chunk;
    if (b < 8) {
        L = 128; chunk = 0;
        ids = q_ids + b * 128; twr = tw + b * 128; eff = eff_q + b * 128;
    } else {
        int pr = (b - 8) >> 1; chunk = (b - 8) & 1; L = 512;
        ids = p_ids + pr * 512; twr = tw + 1024 + pr * 512; eff = eff_p + pr * 512;
    }
    for (int l = t; l < L; l += 256) { sid[l] = ids[l]; stw[l] = twr[l]; }
    __syncthreads();
    int l = chunk * 256 + t;
    if (l < L) {
        int id = sid[l];
        float wv = stw[l];
        bool kill = (id < 4);  // UNUSED ids {0,1,2,3} -> zero
        #pragma unroll 8
        for (int m = 0; m < L; ++m) {
            int idm = sid[m];
            float wm = stw[m];
            bool beats = (idm == id) & (m != l) & ((wm > wv) | ((wm == wv) & (m < l)));
            kill = kill | beats;
        }
        eff[l] = kill ? 0.0f : wv;
    }
}

// ---------------------------------------------------------------------------
// 128x128xK bf16 MFMA GEMM, B^T layout:  C[m,n] = sum_k A[m,k]*B[n,k]
// tile 128x128, BK=64, 256 thr (4 waves, 2x2), 1-D grid with XCD swizzle.
// MODE 0 (projection, M=33792 N=1024 K=1024): blocks [0,2112): id=8t+x ->
//         rowTile = 33x + (t>>3), colTile = t&7  (A-tile reused by 8
//         consecutive same-XCD blocks; W resident).  C_bf16 = res + bias[n];
//         atomicAdd normsq[row].  Blocks [2112,2624) = dense+sparse tail.
// MODE 1 (maxsim, M=1024 N=32768 K=1024): id=8t+x ->
//         colTile = 32x + (t>>3), rowTile = t&7  (each pv tile fetched once,
//         by one XCD; qv resident).  Scale col j by pfac_j, exclude CLS cols,
//         row-max -> atomicMax Mbuf[row*64+pb].
// Staging XOR swizzle (verified R4): lane l loads row r=l>>2, k-chunk
// c=(l&3)^((l>>3)&3); global stays 64B-segment coalesced, LDS fragment
// reads conflict-free at fragOff = (m16*4 + (quad^((m16>>1)&3)))*8.
// ---------------------------------------------------------------------------
template<int MODE>
__global__ __launch_bounds__(256, 2)
void gemm_bt(const unsigned short* __restrict__ A,
             const unsigned short* __restrict__ B,
             const float* __restrict__ bias,
             unsigned short* __restrict__ C,
             unsigned* __restrict__ Mbuf,
             float* __restrict__ normsq,
             const float* __restrict__ p_mask,
             int gemmBlocks, int N, int K,
             // tail-block (dense+sparse) inputs, MODE 0 only:
             const float* __restrict__ qh, const float* __restrict__ ph,
             const int* __restrict__ q_ids, const int* __restrict__ p_ids,
             const float* __restrict__ eff_q, const float* __restrict__ eff_p,
             float* __restrict__ out)
{
    __shared__ unsigned short smA[128 * 64];
    __shared__ unsigned short smB[128 * 64];
    const int tid = threadIdx.x;
    const int blk = blockIdx.x;

    if (MODE == 0 && blk >= gemmBlocks) {
        // ---- dense + sparse tail block ----
        int pair = blk - gemmBlocks;                 // [0,512)
        int qb = pair >> 6, pb = pair & 63;
        char* lds = (char*)smA;
        int*   qid = (int*)lds;                 // 512 B
        float* qef = (float*)(lds + 512);       // 512 B
        int*   pid = (int*)(lds + 1024);        // 2 KB
        float* pef = (float*)(lds + 3072);      // 2 KB
        float* redD = (float*)(lds + 5120);     // 12 floats
        float* redS = (float*)(lds + 5184);     // 4 floats
        int t = tid;
        if (t < 128) { qid[t] = q_ids[qb * 128 + t]; qef[t] = eff_q[qb * 128 + t]; }
        for (int m = t; m < 512; m += 256) { pid[m] = p_ids[pb * 512 + m]; pef[m] = eff_p[pb * 512 + m]; }
        // dense partial (CLS rows)
        const float4* q4 = (const float4*)(qh + (size_t)qb * 128 * 1024);
        const float4* p4 = (const float4*)(ph + (size_t)pb * 512 * 1024);
        float4 a = q4[t], b = p4[t];
        float dot = a.x * b.x + a.y * b.y + a.z * b.z + a.w * b.w;
        float nq  = a.x * a.x + a.y * a.y + a.z * a.z + a.w * a.w;
        float np  = b.x * b.x + b.y * b.y + b.z * b.z + b.w * b.w;
        #pragma unroll
        for (int sh = 32; sh; sh >>= 1) {
            dot += __shfl_down(dot, sh, 64);
            nq  += __shfl_down(nq, sh, 64);
            np  += __shfl_down(np, sh, 64);
        }
        if ((t & 63) == 0) { int w = t >> 6; redD[w] = dot; redD[4 + w] = nq; redD[8 + w] = np; }
        __syncthreads();
        if (t == 0) {
            float d = redD[0] + redD[1] + redD[2] + redD[3];
            float n1 = redD[4] + redD[5] + redD[6] + redD[7];
            float n2 = redD[8] + redD[9] + redD[10] + redD[11];
            out[qb * 64 + pb] = d / (fmaxf(sqrtf(n1), 1e-12f) * fmaxf(sqrtf(n2), 1e-12f)) / TEMP;
        }
        // sparse: sum over matching ids
        float s = 0.0f;
        for (int idx = t; idx < 128 * 512; idx += 256) {
            int l = idx >> 9, m = idx & 511;
            if (qid[l] == pid[m]) s += qef[l] * pef[m];
        }
        #pragma unroll
        for (int sh = 32; sh; sh >>= 1) s += __shfl_down(s, sh, 64);
        if ((t & 63) == 0) redS[t >> 6] = s;
        __syncthreads();
        if (t == 0) out[512 + qb * 64 + pb] = (redS[0] + redS[1] + redS[2] + redS[3]) / TEMP;
        return;
    }

    const int lane = tid & 63;
    const int w    = tid >> 6;
    const int wm   = w >> 1, wn = w & 1;
    const int quad = lane >> 4, m16 = lane & 15;

    // XCD-chunked swizzle (XCD = blk & 7 heuristic; perf-only)
    int rowTile, colTile;
    {
        int x = blk & 7, t = blk >> 3;
        if (MODE == 0) { rowTile = x * 33 + (t >> 3); colTile = t & 7; }
        else           { colTile = x * 32 + (t >> 3); rowTile = t & 7; }
    }
    const int rowBase = rowTile * 128;
    const int colBase = colTile * 128;

    // staging lane decomposition (XOR swizzle)
    const int sr = lane >> 2;
    const int scg = (lane & 3) ^ ((lane >> 3) & 3);
    const unsigned short* aG0 = A + (long long)(rowBase + w * 16 + sr) * K + scg * 8;
    const unsigned short* aG1 = aG0 + 64LL * K;
    const unsigned short* bG0 = B + (long long)(colBase + w * 16 + sr) * K + scg * 8;
    const unsigned short* bG1 = bG0 + 64LL * K;
    unsigned short* lA0 = smA + w * 512;          // khalf 0 at +0, khalf 1 at +4096
    unsigned short* lA1 = smA + (w + 4) * 512;
    unsigned short* lB0 = smB + w * 512;
    unsigned short* lB1 = smB + (w + 4) * 512;

    const int fragOff = (m16 * 4 + (quad ^ ((m16 >> 1) & 3))) * 8;

    floatx4 acc[4][4] = {};

    for (int k0 = 0; k0 < K; k0 += 64) {
        async_load16(lA0,        aG0 + k0);
        async_load16(lA0 + 4096, aG0 + k0 + 32);
        async_load16(lA1,        aG1 + k0);
        async_load16(lA1 + 4096, aG1 + k0 + 32);
        async_load16(lB0,        bG0 + k0);
        async_load16(lB0 + 4096, bG0 + k0 + 32);
        async_load16(lB1,        bG1 + k0);
        async_load16(lB1 + 4096, bG1 + k0 + 32);
        __syncthreads();
        #pragma unroll
        for (int h = 0; h < 2; ++h) {
            bf16x8 af[4], bfr[4];
            #pragma unroll
            for (int f = 0; f < 4; ++f) {
                af[f]  = *(const bf16x8*)(smA + h * 4096 + (wm * 4 + f) * 512 + fragOff);
                bfr[f] = *(const bf16x8*)(smB + h * 4096 + (wn * 4 + f) * 512 + fragOff);
            }
            #pragma unroll
            for (int i = 0; i < 4; ++i)
                #pragma unroll
                for (int j = 0; j < 4; ++j)
                    acc[i][j] = __builtin_amdgcn_mfma_f32_16x16x32_bf16(af[i], bfr[j], acc[i][j], 0, 0, 0);
        }
        __syncthreads();
    }

    if (MODE == 0) {
        float bcol[4];
        #pragma unroll
        for (int j = 0; j < 4; ++j) bcol[j] = bias[colBase + wn * 64 + j * 16 + m16];
        #pragma unroll
        for (int i = 0; i < 4; ++i) {
            int row0 = rowBase + wm * 64 + i * 16 + quad * 4;
            #pragma unroll
            for (int r = 0; r < 4; ++r) {
                float sq = 0.0f;
                #pragma unroll
                for (int j = 0; j < 4; ++j) {
                    int col = colBase + wn * 64 + j * 16 + m16;
                    float val = acc[i][j][r] + bcol[j];
                    C[(long long)(row0 + r) * N + col] = f2bf(val);
                    sq += val * val;
                }
                #pragma unroll
                for (int s = 1; s < 16; s <<= 1) sq += __shfl_xor(sq, s, 64);
                if (m16 == 0) atomicAdd(&normsq[row0 + r], sq);
            }
        }
    } else {
        const int pb = colBase >> 9;  // 512 p-tokens per passage
        float pfac[4];
        #pragma unroll
        for (int j = 0; j < 4; ++j) {
            int colg = colBase + wn * 64 + j * 16 + m16;
            float pm = p_mask[colg];
            float pn = sqrtf(normsq[1024 + colg]);
            pfac[j] = pm / fmaxf(pn * pm, 1e-12f);
        }
        #pragma unroll
        for (int i = 0; i < 4; ++i) {
            #pragma unroll
            for (int r = 0; r < 4; ++r) {
                float mx = -3.0e38f;
                #pragma unroll
                for (int j = 0; j < 4; ++j) {
                    int colg = colBase + wn * 64 + j * 16 + m16;
                    float v = acc[i][j][r] * pfac[j];
                    if ((colg & 511) == 0) v = -3.0e38f;  // exclude CLS column
                    mx = fmaxf(mx, v);
                }
                #pragma unroll
                for (int s = 1; s < 16; s <<= 1) mx = fmaxf(mx, __shfl_xor(mx, s, 64));
                if (m16 == 0) {
                    int row = rowBase + wm * 64 + i * 16 + quad * 4 + r;
                    atomicMax(&Mbuf[row * 64 + pb], encf(mx));
                }
            }
        }
    }
}

// ---------------------------------------------------------------------------
// colbert final reduce: out = sum_{i>=1} dec(M[i,pb])*qfac_i / msum / TEMP
// qfac_i = qm/max(||v_i||*qm, eps)  (deferred per-row normalization)
// ---------------------------------------------------------------------------
__global__ void colbert_reduce_k(const unsigned* __restrict__ Mbuf,
                                 const float* __restrict__ q_mask,
                                 const float* __restrict__ normsq,
                                 float* __restrict__ out)
{
    int pair = blockIdx.x * 4 + (threadIdx.x >> 6);
    int lane = threadIdx.x & 63;
    int qb = pair >> 6, pb = pair & 63;
    float s = 0.0f, msum = 0.0f;
    for (int i = 1 + lane; i < 128; i += 64) {
        float qm = q_mask[qb * 128 + i];
        float qn = sqrtf(normsq[qb * 128 + i]);
        float qfac = qm / fmaxf(qn * qm, 1e-12f);
        s += decf(Mbuf[(qb * 128 + i) * 64 + pb]) * qfac;
        msum += qm;
    }
    #pragma unroll
    for (int sh = 32; sh; sh >>= 1) {
        s += __shfl_down(s, sh, 64);
        msum += __shfl_down(msum, sh, 64);
    }
    if (lane == 0) out[1024 + qb * 64 + pb] = s / msum / TEMP;
}

// ---------------------------------------------------------------------------
extern "C" void kernel_launch(void* const* d_in, const int* in_sizes, int n_in,
                              void* d_out, int out_size, void* d_ws, size_t ws_size,
                              hipStream_t stream)
{
    const float* q_hidden = (const float*)d_in[0];   // [8,128,1024]
    const float* p_hidden = (const float*)d_in[1];   // [64,512,1024]
    const float* q_mask   = (const float*)d_in[2];   // [8,128]
    const float* p_mask   = (const float*)d_in[3];   // [64,512]
    const int*   q_ids    = (const int*)d_in[4];     // [8,128]
    const int*   p_ids    = (const int*)d_in[5];     // [64,512]
    const float* colbert_w = (const float*)d_in[6];  // [1024,1024]
    const float* colbert_b = (const float*)d_in[7];  // [1024]
    const float* sparse_w  = (const float*)d_in[8];  // [1024]
    const float* sparse_b  = (const float*)d_in[9];  // [1]
    float* out = (float*)d_out;                      // [3*512]

    // workspace carve-up (~135 MB). qhb|phb|Wb contiguous; qv|pv contiguous;
    // Mbuf|normsq contiguous (zeroed inside conv_zero_tw).
    char* ws = (char*)d_ws;
    size_t off = 0;
    auto carve = [&](size_t bytes) { char* p = ws + off; off += (bytes + 255) & ~(size_t)255; return p; };
    unsigned short* qhb  = (unsigned short*)carve((size_t)1024 * 1024 * 2);
    unsigned short* phb  = (unsigned short*)carve((size_t)32768 * 1024 * 2);
    unsigned short* Wb   = (unsigned short*)carve((size_t)1024 * 1024 * 2);
    unsigned short* qv   = (unsigned short*)carve((size_t)1024 * 1024 * 2);
    unsigned short* pv   = (unsigned short*)carve((size_t)32768 * 1024 * 2);
    unsigned* Mbuf  = (unsigned*)carve((size_t)1024 * 64 * 4);        // 256 KB
    float*    normsq = (float*)carve((size_t)33792 * 4);              // 132 KB (adjacent)
    float*    tw    = (float*)carve((size_t)33792 * 4);
    float*    eff_q = (float*)carve(1024 * 4);
    float*    eff_p = (float*)carve(32768 * 4);
    (void)phb; (void)Wb; (void)pv;

    // 1. fused bf16 conversion (q,p,W) + token weights + zero Mbuf/normsq
    conv_zero_tw<<<17408, 256, 0, stream>>>(q_hidden, p_hidden, colbert_w, qhb,
                                            sparse_w, sparse_b, tw, Mbuf);

    // 2. sparse canonicalization (q + p in one grid)
    canon_all<<<136, 256, 0, stream>>>(q_ids, p_ids, tw, eff_q, eff_p);

    // 3. projection GEMM over concat(q,p): 2112 GEMM blocks (XCD-swizzled)
    //    + 512 tail blocks computing dense + sparse scores concurrently
    gemm_bt<0><<<2112 + 512, 256, 0, stream>>>(
        qhb, Wb, colbert_b, qv, nullptr, normsq, nullptr, 2112, 1024, 1024,
        q_hidden, p_hidden, q_ids, p_ids, eff_q, eff_p, out);

    // 4. maxsim GEMM with fused per-col normalization + max epilogue
    gemm_bt<1><<<2048, 256, 0, stream>>>(
        qv, pv, nullptr, nullptr, Mbuf, normsq, p_mask, 2048, 32768, 1024,
        nullptr, nullptr, nullptr, nullptr, nullptr, nullptr, nullptr);

    // 5. colbert final reduce (needs all maxsim blocks done)
    colbert_reduce_k<<<128, 256, 0, stream>>>(Mbuf, q_mask, normsq, out);
}